// Round 5
// baseline (1508.237 us; speedup 1.0000x reference)
//
#include <hip/hip_runtime.h>

#define NROWS 131072
#define DIM   128
#define FFD   512
#define TSTEPS 4
#define NBLK  512
#define NSLOT 16
#define SH    136  // stride (shorts) for 128-wide bf16 LDS tiles
#define SKV   72   // stride for 64-wide bf16 LDS tiles (KT/VT)
#define ACH   64   // kA rows per chunk
#define ANCH  4
#define BCH   128  // kB rows per chunk
#define BNCH  2

static_assert((long)NBLK*ACH*ANCH == NROWS, "kA grid");
static_assert((long)NBLK*BCH*BNCH == NROWS, "kB grid");

typedef short          s8v   __attribute__((ext_vector_type(8)));
typedef float          f4v   __attribute__((ext_vector_type(4)));
typedef unsigned short u16x4 __attribute__((ext_vector_type(4)));

#define MFMA16(a,b,c) __builtin_amdgcn_mfma_f32_16x16x32_bf16((a),(b),(c),0,0,0)

__device__ __forceinline__ unsigned short f2bf(float f){
    unsigned u = __builtin_bit_cast(unsigned, f);
    u += 0x7FFFu + ((u >> 16) & 1u);
    return (unsigned short)(u >> 16);
}
__device__ __forceinline__ float bf2f(unsigned short h){
    return __builtin_bit_cast(float, (unsigned)h << 16);
}

__device__ __forceinline__ float2 ln_pair(float2 xv, float g0, float g1, float b0, float b1){
    float s = xv.x + xv.y;
    float q = xv.x*xv.x + xv.y*xv.y;
    #pragma unroll
    for (int o = 1; o < 64; o <<= 1) { s += __shfl_xor(s, o); q += __shfl_xor(q, o); }
    const float m  = s * (1.0f/128.0f);
    const float rs = rsqrtf(q * (1.0f/128.0f) - m*m + 1e-5f);
    return make_float2((xv.x - m)*rs*g0 + b0, (xv.y - m)*rs*g1 + b1);
}

template<bool SPLIT>
__device__ __forceinline__ void store_h(unsigned short* hi, unsigned short* lo,
                                        int off, float2 h){
    const unsigned short h0 = f2bf(h.x), h1 = f2bf(h.y);
    *(unsigned*)&hi[off] = (unsigned)h0 | ((unsigned)h1 << 16);
    if (SPLIT) {
        const unsigned short l0 = f2bf(h.x - bf2f(h0)), l1 = f2bf(h.y - bf2f(h1));
        *(unsigned*)&lo[off] = (unsigned)l0 | ((unsigned)l1 << 16);
    }
}

// ---------------------------------------------------------------------------
// Kernel A: LN1 (split bf16), K/V projections, partial KtV -> atomic slots.
// ---------------------------------------------------------------------------
__global__ __launch_bounds__(256, 2)
void kA(const float* __restrict__ x, const unsigned short* __restrict__ Kwp,
        const unsigned short* __restrict__ Vwp,
        const float* __restrict__ ga, const float* __restrict__ be,
        float* __restrict__ slots)
{
    __shared__ unsigned short hh[ACH*SH];
    __shared__ unsigned short hl[ACH*SH];
    __shared__ unsigned short KT[128*SKV];
    __shared__ unsigned short VT[128*SKV];
    const int tid  = threadIdx.x;
    const int wv   = tid >> 6, lane = tid & 63;
    const int quad = lane >> 4, l15 = lane & 15;

    f4v acc[16];
    #pragma unroll
    for (int i = 0; i < 16; ++i) acc[i] = (f4v){0.f,0.f,0.f,0.f};

    const float g0 = ga[2*lane], g1 = ga[2*lane+1];
    const float b0 = be[2*lane], b1 = be[2*lane+1];

    // B-fragments for K/V projections: loop-invariant -> load once
    s8v bk[2][4], bv[2][4];
    #pragma unroll
    for (int nt = 0; nt < 2; ++nt)
        #pragma unroll
        for (int ks = 0; ks < 4; ++ks) {
            bk[nt][ks] = *(const s8v*)(Kwp + (wv*32 + nt*16 + l15)*DIM + ks*32 + quad*8);
            bv[nt][ks] = *(const s8v*)(Vwp + (wv*32 + nt*16 + l15)*DIM + ks*32 + quad*8);
        }

    for (int ch = 0; ch < ANCH; ++ch) {
        const size_t r0 = ((size_t)blockIdx.x*ANCH + ch)*ACH;
        #pragma unroll
        for (int rr = 0; rr < 16; ++rr) {
            const int r = wv*16 + rr;
            const float2 xv = *(const float2*)(x + (r0 + r)*DIM + 2*lane);
            store_h<true>(hh, hl, r*SH + 2*lane, ln_pair(xv, g0, g1, b0, b1));
        }
        __syncthreads();
        #pragma unroll
        for (int p = 0; p < 2; ++p) {
            unsigned short* T = p ? VT : KT;
            #pragma unroll
            for (int mt = 0; mt < 4; ++mt) {
                s8v ah[4], al[4];
                #pragma unroll
                for (int ks = 0; ks < 4; ++ks) {
                    ah[ks] = *(const s8v*)(&hh[(mt*16 + l15)*SH + ks*32 + quad*8]);
                    al[ks] = *(const s8v*)(&hl[(mt*16 + l15)*SH + ks*32 + quad*8]);
                }
                #pragma unroll
                for (int nt = 0; nt < 2; ++nt) {
                    f4v c = {0.f,0.f,0.f,0.f};
                    #pragma unroll
                    for (int ks = 0; ks < 4; ++ks) c = MFMA16(ah[ks], p ? bv[nt][ks] : bk[nt][ks], c);
                    #pragma unroll
                    for (int ks = 0; ks < 4; ++ks) c = MFMA16(al[ks], p ? bv[nt][ks] : bk[nt][ks], c);
                    u16x4 w4 = { f2bf(c[0]), f2bf(c[1]), f2bf(c[2]), f2bf(c[3]) };
                    *(u16x4*)&T[(wv*32 + nt*16 + l15)*SKV + mt*16 + quad*4] = w4;
                }
            }
        }
        __syncthreads();
        #pragma unroll
        for (int ks = 0; ks < 2; ++ks) {
            s8v af[2];
            #pragma unroll
            for (int it = 0; it < 2; ++it)
                af[it] = *(const s8v*)(&KT[(wv*32 + it*16 + l15)*SKV + ks*32 + quad*8]);
            #pragma unroll
            for (int jt = 0; jt < 8; ++jt) {
                const s8v bfr = *(const s8v*)(&VT[(jt*16 + l15)*SKV + ks*32 + quad*8]);
                #pragma unroll
                for (int it = 0; it < 2; ++it)
                    acc[jt*2 + it] = MFMA16(af[it], bfr, acc[jt*2 + it]);
            }
        }
        __syncthreads();
    }
    float* S = slots + (size_t)(blockIdx.x & (NSLOT-1)) * 16384;
    #pragma unroll
    for (int jt = 0; jt < 8; ++jt)
        #pragma unroll
        for (int it = 0; it < 2; ++it) {
            const int i0 = wv*32 + it*16 + quad*4;
            const int j  = jt*16 + l15;
            #pragma unroll
            for (int rg = 0; rg < 4; ++rg)
                atomicAdd(&S[(i0 + rg)*DIM + j], acc[jt*2 + it][rg]);
        }
}

// Reduce NSLOT partials -> ktv; zero slots for the next step's kA.
__global__ void kReduce(float* __restrict__ slots, float* __restrict__ ktv)
{
    const int e = blockIdx.x*256 + threadIdx.x;
    float s = 0.f;
    #pragma unroll
    for (int b = 0; b < NSLOT; ++b) s += slots[(size_t)b*16384 + e];
    ktv[e] = s;
    #pragma unroll
    for (int b = 0; b < NSLOT; ++b) slots[(size_t)b*16384 + e] = 0.f;
}

// M = Qw @ KtV, split bf16 in B-operand [n][k] layout
__global__ void kBuildM(const float* __restrict__ Qw, const float* __restrict__ ktv,
                        unsigned short* __restrict__ Mp, unsigned short* __restrict__ Ml)
{
    const int idx = blockIdx.x*256 + threadIdx.x;
    const int j = idx >> 7, k = idx & 127;
    float s = 0.f;
    for (int i = 0; i < 128; ++i) s += Qw[k*128 + i] * ktv[i*128 + j];
    const unsigned short hi = f2bf(s);
    Mp[idx] = hi;
    Ml[idx] = f2bf(s - bf2f(hi));
}

// ---------------------------------------------------------------------------
// Kernel B: x += h1@M ; LN2 ; x += relu(h2@w1+b1)@w2 + b2.  Residual x lives
// in registers (MFMA C-layout); GEMMs accumulate directly into it.
// ---------------------------------------------------------------------------
__global__ __launch_bounds__(256, 2)
void kB(const float* __restrict__ xin, float* __restrict__ xout,
        const unsigned short* __restrict__ Mp, const unsigned short* __restrict__ Ml,
        const float* __restrict__ g1a, const float* __restrict__ b1a,
        const float* __restrict__ g2a, const float* __restrict__ b2a,
        const unsigned short* __restrict__ w1p, const float* __restrict__ fb1,
        const unsigned short* __restrict__ w2p, const float* __restrict__ fb2)
{
    __shared__ unsigned short hs[BCH*SH];    // h (hi)
    __shared__ unsigned short hlfb[BCH*SH];  // h1-lo during GEMM1; f tile during FF
    __shared__ float2 part[BCH][4];          // per-wave LN partials (sum, sumsq)
    __shared__ float2 stat[BCH];             // per-row (mean, rstd)

    const int tid  = threadIdx.x;
    const int wv   = tid >> 6, lane = tid & 63;
    const int quad = lane >> 4, l15 = lane & 15;
    const int cg0  = wv*32 + l15, cg1 = cg0 + 16;

    const float g1c[2] = { g1a[cg0], g1a[cg1] };
    const float b1c[2] = { b1a[cg0], b1a[cg1] };
    const float g2c[2] = { g2a[cg0], g2a[cg1] };
    const float b2c[2] = { b2a[cg0], b2a[cg1] };
    const float ob2[2] = { fb2[cg0], fb2[cg1] };

    for (int ch = 0; ch < BNCH; ++ch) {
        const size_t r0 = ((size_t)blockIdx.x*BNCH + ch)*BCH;
        f4v xr[8][2];   // rows 16mt+4quad+rg, col cg[nt]
        // --- load x into C-layout regs + LN1 partials ---
        #pragma unroll
        for (int mt = 0; mt < 8; ++mt) {
            const float* rp = xin + (r0 + 16*mt + 4*quad)*DIM;
            #pragma unroll
            for (int nt = 0; nt < 2; ++nt) {
                const int cg = nt ? cg1 : cg0;
                #pragma unroll
                for (int rg = 0; rg < 4; ++rg)
                    xr[mt][nt][rg] = rp[rg*DIM + cg];
            }
            #pragma unroll
            for (int rg = 0; rg < 4; ++rg) {
                float s = xr[mt][0][rg] + xr[mt][1][rg];
                float q = xr[mt][0][rg]*xr[mt][0][rg] + xr[mt][1][rg]*xr[mt][1][rg];
                #pragma unroll
                for (int o = 1; o < 16; o <<= 1) { s += __shfl_xor(s,o); q += __shfl_xor(q,o); }
                if (l15 == 0) part[16*mt + 4*quad + rg][wv] = make_float2(s, q);
            }
        }
        __syncthreads();                                   // B1
        if (tid < BCH) {
            const float2 p0=part[tid][0], p1=part[tid][1], p2=part[tid][2], p3=part[tid][3];
            const float S = p0.x+p1.x+p2.x+p3.x, SS = p0.y+p1.y+p2.y+p3.y;
            const float m = S*(1.f/128.f);
            stat[tid] = make_float2(m, rsqrtf(SS*(1.f/128.f) - m*m + 1e-5f));
        }
        __syncthreads();                                   // B2
        // --- h1 (split) -> hs / hlfb ---
        #pragma unroll
        for (int mt = 0; mt < 8; ++mt)
            #pragma unroll
            for (int rg = 0; rg < 4; ++rg) {
                const float2 st = stat[16*mt + 4*quad + rg];
                const int ro = (16*mt + 4*quad + rg)*SH;
                #pragma unroll
                for (int nt = 0; nt < 2; ++nt) {
                    const float h = (xr[mt][nt][rg] - st.x)*st.y*g1c[nt] + b1c[nt];
                    const unsigned short hi = f2bf(h);
                    hs[ro + (nt?cg1:cg0)]   = hi;
                    hlfb[ro + (nt?cg1:cg0)] = f2bf(h - bf2f(hi));
                }
            }
        __syncthreads();                                   // B3
        // --- GEMM1: xr += h1 @ M (3-way split) ---
        {
            s8v bh[2][4], bl[2][4];
            #pragma unroll
            for (int nt = 0; nt < 2; ++nt)
                #pragma unroll
                for (int ks = 0; ks < 4; ++ks) {
                    bh[nt][ks] = *(const s8v*)(Mp + (wv*32 + nt*16 + l15)*DIM + ks*32 + quad*8);
                    bl[nt][ks] = *(const s8v*)(Ml + (wv*32 + nt*16 + l15)*DIM + ks*32 + quad*8);
                }
            #pragma unroll
            for (int mt = 0; mt < 8; ++mt) {
                s8v ah[4], al[4];
                #pragma unroll
                for (int ks = 0; ks < 4; ++ks) {
                    ah[ks] = *(const s8v*)(&hs[(mt*16 + l15)*SH + ks*32 + quad*8]);
                    al[ks] = *(const s8v*)(&hlfb[(mt*16 + l15)*SH + ks*32 + quad*8]);
                }
                #pragma unroll
                for (int nt = 0; nt < 2; ++nt) {
                    f4v c = xr[mt][nt];
                    #pragma unroll
                    for (int ks = 0; ks < 4; ++ks) c = MFMA16(ah[ks], bh[nt][ks], c);
                    #pragma unroll
                    for (int ks = 0; ks < 4; ++ks) c = MFMA16(ah[ks], bl[nt][ks], c);
                    #pragma unroll
                    for (int ks = 0; ks < 4; ++ks) c = MFMA16(al[ks], bh[nt][ks], c);
                    xr[mt][nt] = c;
                }
            }
        }
        // --- LN2 partials (xr updated; part buffer free since B2) ---
        #pragma unroll
        for (int mt = 0; mt < 8; ++mt)
            #pragma unroll
            for (int rg = 0; rg < 4; ++rg) {
                float s = xr[mt][0][rg] + xr[mt][1][rg];
                float q = xr[mt][0][rg]*xr[mt][0][rg] + xr[mt][1][rg]*xr[mt][1][rg];
                #pragma unroll
                for (int o = 1; o < 16; o <<= 1) { s += __shfl_xor(s,o); q += __shfl_xor(q,o); }
                if (l15 == 0) part[16*mt + 4*quad + rg][wv] = make_float2(s, q);
            }
        __syncthreads();                                   // B4
        if (tid < BCH) {
            const float2 p0=part[tid][0], p1=part[tid][1], p2=part[tid][2], p3=part[tid][3];
            const float S = p0.x+p1.x+p2.x+p3.x, SS = p0.y+p1.y+p2.y+p3.y;
            const float m = S*(1.f/128.f);
            stat[tid] = make_float2(m, rsqrtf(SS*(1.f/128.f) - m*m + 1e-5f));
        }
        __syncthreads();                                   // B5
        // --- h2 (hi only) -> hs ---
        #pragma unroll
        for (int mt = 0; mt < 8; ++mt)
            #pragma unroll
            for (int rg = 0; rg < 4; ++rg) {
                const float2 st = stat[16*mt + 4*quad + rg];
                const int ro = (16*mt + 4*quad + rg)*SH;
                #pragma unroll
                for (int nt = 0; nt < 2; ++nt)
                    hs[ro + (nt?cg1:cg0)] = f2bf((xr[mt][nt][rg] - st.x)*st.y*g2c[nt] + b2c[nt]);
            }
        __syncthreads();                                   // B6
        // --- FF: 4 quarters of 128 ff-cols; GEMM2b accumulates into xr ---
        #pragma unroll
        for (int qf = 0; qf < 4; ++qf) {
            // GEMM2a: f = relu(h2 @ w1[:,q] + b1) -> hlfb
            {
                s8v w1f[2][4];
                float bias[2];
                #pragma unroll
                for (int nt = 0; nt < 2; ++nt) {
                    const int ffc = qf*128 + (nt?cg1:cg0);
                    bias[nt] = fb1[ffc];
                    #pragma unroll
                    for (int ks = 0; ks < 4; ++ks)
                        w1f[nt][ks] = *(const s8v*)(w1p + ffc*DIM + ks*32 + quad*8);
                }
                #pragma unroll
                for (int mt = 0; mt < 8; ++mt) {
                    s8v ah[4];
                    #pragma unroll
                    for (int ks = 0; ks < 4; ++ks)
                        ah[ks] = *(const s8v*)(&hs[(mt*16 + l15)*SH + ks*32 + quad*8]);
                    #pragma unroll
                    for (int nt = 0; nt < 2; ++nt) {
                        f4v c = {0.f,0.f,0.f,0.f};
                        #pragma unroll
                        for (int ks = 0; ks < 4; ++ks) c = MFMA16(ah[ks], w1f[nt][ks], c);
                        #pragma unroll
                        for (int rg = 0; rg < 4; ++rg) {
                            float v = c[rg] + bias[nt];
                            v = v > 0.f ? v : 0.f;
                            hlfb[(16*mt + 4*quad + rg)*SH + (nt?cg1:cg0)] = f2bf(v);
                        }
                    }
                }
            }
            __syncthreads();
            // GEMM2b: xr += f @ w2[q,:]
            {
                s8v w2f[2][4];
                #pragma unroll
                for (int nt = 0; nt < 2; ++nt)
                    #pragma unroll
                    for (int ks = 0; ks < 4; ++ks)
                        w2f[nt][ks] = *(const s8v*)(w2p + (nt?cg1:cg0)*FFD + qf*128 + ks*32 + quad*8);
                #pragma unroll
                for (int mt = 0; mt < 8; ++mt) {
                    s8v af[4];
                    #pragma unroll
                    for (int ks = 0; ks < 4; ++ks)
                        af[ks] = *(const s8v*)(&hlfb[(mt*16 + l15)*SH + ks*32 + quad*8]);
                    #pragma unroll
                    for (int nt = 0; nt < 2; ++nt) {
                        f4v c = xr[mt][nt];
                        #pragma unroll
                        for (int ks = 0; ks < 4; ++ks) c = MFMA16(af[ks], w2f[nt][ks], c);
                        xr[mt][nt] = c;
                    }
                }
            }
            __syncthreads();
        }
        // --- epilogue (+b2) + store (in-place safe: block owns its rows) ---
        #pragma unroll
        for (int mt = 0; mt < 8; ++mt) {
            float* rp = xout + (r0 + 16*mt + 4*quad)*DIM;
            #pragma unroll
            for (int nt = 0; nt < 2; ++nt) {
                const int cg = nt ? cg1 : cg0;
                #pragma unroll
                for (int rg = 0; rg < 4; ++rg)
                    rp[rg*DIM + cg] = xr[mt][nt][rg] + ob2[nt];
            }
        }
    }
}

// ---------------------------------------------------------------------------
// Final: out = x @ out_w + out_b  (split-x, in-place safe on d_out)
// ---------------------------------------------------------------------------
__global__ __launch_bounds__(256, 2)
void kF(const float* __restrict__ x, const unsigned short* __restrict__ Owp,
        const float* __restrict__ ob, float* __restrict__ out)
{
    __shared__ unsigned short hh[64*SH];
    __shared__ unsigned short hl[64*SH];
    __shared__ float          xb[64*132];
    const int tid  = threadIdx.x;
    const int wv   = tid >> 6, lane = tid & 63;
    const int quad = lane >> 4, l15 = lane & 15;
    (void)lane;

    s8v bf[2][4];
    #pragma unroll
    for (int nt = 0; nt < 2; ++nt)
        #pragma unroll
        for (int ks = 0; ks < 4; ++ks)
            bf[nt][ks] = *(const s8v*)(Owp + (wv*32 + nt*16 + l15)*DIM + ks*32 + quad*8);

    for (int ch = 0; ch < ANCH; ++ch) {
        const size_t r0 = ((size_t)blockIdx.x*ANCH + ch)*ACH;
        #pragma unroll
        for (int i = 0; i < 8; ++i) {
            const int idx = tid + i*256;
            const int r = idx >> 5, c = (idx & 31)*4;
            const float4 v = *(const float4*)(x + (r0 + r)*DIM + c);
            const unsigned short h0 = f2bf(v.x), h1 = f2bf(v.y),
                                 h2 = f2bf(v.z), h3 = f2bf(v.w);
            u16x4 w4 = { h0, h1, h2, h3 };
            u16x4 l4 = { f2bf(v.x - bf2f(h0)), f2bf(v.y - bf2f(h1)),
                         f2bf(v.z - bf2f(h2)), f2bf(v.w - bf2f(h3)) };
            *(u16x4*)&hh[r*SH + c] = w4;
            *(u16x4*)&hl[r*SH + c] = l4;
        }
        __syncthreads();
        #pragma unroll
        for (int mt = 0; mt < 4; ++mt) {
            s8v ah[4], al[4];
            #pragma unroll
            for (int ks = 0; ks < 4; ++ks) {
                ah[ks] = *(const s8v*)(&hh[(mt*16 + l15)*SH + ks*32 + quad*8]);
                al[ks] = *(const s8v*)(&hl[(mt*16 + l15)*SH + ks*32 + quad*8]);
            }
            #pragma unroll
            for (int nt = 0; nt < 2; ++nt) {
                f4v c = {0.f,0.f,0.f,0.f};
                #pragma unroll
                for (int ks = 0; ks < 4; ++ks) c = MFMA16(ah[ks], bf[nt][ks], c);
                #pragma unroll
                for (int ks = 0; ks < 4; ++ks) c = MFMA16(al[ks], bf[nt][ks], c);
                const int cg = wv*32 + nt*16 + l15;
                const float bias = ob[cg];
                #pragma unroll
                for (int rg = 0; rg < 4; ++rg)
                    xb[(mt*16 + quad*4 + rg)*132 + cg] = c[rg] + bias;
            }
        }
        __syncthreads();
        #pragma unroll
        for (int i = 0; i < 8; ++i) {
            const int idx = tid + i*256;
            const int r = idx >> 5, c = (idx & 31)*4;
            *(float4*)(out + (r0 + r)*DIM + c) = *(const float4*)&xb[r*132 + c];
        }
        __syncthreads();
    }
}

// Pack weights to bf16 [n][k] layout; also zero the KtV slots for step 0.
__global__ void kPack(const float* __restrict__ Kw, const float* __restrict__ Vw,
                      const float* __restrict__ Ow, const float* __restrict__ w1,
                      const float* __restrict__ w2,
                      unsigned short* __restrict__ Kwp, unsigned short* __restrict__ Vwp,
                      unsigned short* __restrict__ Owp, unsigned short* __restrict__ w1p,
                      unsigned short* __restrict__ w2p, float* __restrict__ slots)
{
    const int t = blockIdx.x*256 + threadIdx.x;  // grid covers 262144
    if (t < 16384) {
        const int n = t >> 7, k = t & 127;
        Kwp[t] = f2bf(Kw[k*128 + n]);
        Vwp[t] = f2bf(Vw[k*128 + n]);
        Owp[t] = f2bf(Ow[k*128 + n]);
    } else if (t < 16384 + 65536) {
        const int u = t - 16384;
        const int n = u >> 7, k = u & 127;
        w1p[u] = f2bf(w1[k*FFD + n]);
    } else if (t < 16384 + 65536 + 65536) {
        const int u = t - 16384 - 65536;
        const int n = u >> 9, k = u & 511;
        w2p[u] = f2bf(w2[k*DIM + n]);
    }
    if (t < NSLOT*16384) slots[t] = 0.f;
}

extern "C" void kernel_launch(void* const* d_in, const int* in_sizes, int n_in,
                              void* d_out, int out_size, void* d_ws, size_t ws_size,
                              hipStream_t stream)
{
    (void)in_sizes; (void)n_in; (void)out_size; (void)ws_size;
    const float* x_in = (const float*)d_in[0];
    const float* Kw   = (const float*)d_in[1];
    const float* Qw   = (const float*)d_in[2];
    const float* Vw   = (const float*)d_in[3];
    const float* ln1g = (const float*)d_in[4];
    const float* ln1b = (const float*)d_in[5];
    const float* ln2g = (const float*)d_in[6];
    const float* ln2b = (const float*)d_in[7];
    const float* w1   = (const float*)d_in[8];
    const float* b1   = (const float*)d_in[9];
    const float* w2   = (const float*)d_in[10];
    const float* b2   = (const float*)d_in[11];
    const float* Ow   = (const float*)d_in[12];
    const float* ob   = (const float*)d_in[13];

    char* p = (char*)d_ws;
    float* slots        = (float*)p;          p += (size_t)NSLOT*16384*4;
    float* ktv          = (float*)p;          p += 16384*4;
    unsigned short* Kwp = (unsigned short*)p; p += 16384*2;
    unsigned short* Vwp = (unsigned short*)p; p += 16384*2;
    unsigned short* Owp = (unsigned short*)p; p += 16384*2;
    unsigned short* w1p = (unsigned short*)p; p += 65536*2;
    unsigned short* w2p = (unsigned short*)p; p += 65536*2;
    unsigned short* Mp  = (unsigned short*)p; p += 16384*2;
    unsigned short* Ml  = (unsigned short*)p; p += 16384*2;

    float* X = (float*)d_out;

    kPack<<<1024, 256, 0, stream>>>(Kw, Vw, Ow, w1, w2, Kwp, Vwp, Owp, w1p, w2p, slots);

    const float* src = x_in;
    for (int t = 0; t < TSTEPS; ++t) {
        kA<<<NBLK, 256, 0, stream>>>(src, Kwp, Vwp, ln1g, ln1b, slots);
        kReduce<<<64, 256, 0, stream>>>(slots, ktv);
        kBuildM<<<64, 256, 0, stream>>>(Qw, ktv, Mp, Ml);
        kB<<<NBLK, 256, 0, stream>>>(src, X, Mp, Ml, ln1g, ln1b, ln2g, ln2b,
                                     w1p, b1, w2p, b2);
        src = X;
    }
    kF<<<NBLK, 256, 0, stream>>>(X, Owp, ob, (float*)d_out);
}